// Round 4
// baseline (237.331 us; speedup 1.0000x reference)
//
#include <hip/hip_runtime.h>
#include <hip/hip_bf16.h>

#define BB 8
#define SS 4096
#define DD 1024
#define LL 16
#define SPAD 1032   // summ LDS row stride (halfwords): +8 pad keeps b128 16B-aligned, even bank spread

typedef __attribute__((ext_vector_type(8))) short short8;
typedef __attribute__((ext_vector_type(4))) float fl4;

static __device__ __forceinline__ short f2bf(float f) {
    // round-to-nearest-even fp32 -> bf16 (inputs finite, no NaN path needed)
    unsigned u = __float_as_uint(f);
    u += 0x7FFFu + ((u >> 16) & 1u);
    return (short)(u >> 16);
}

// One block = one (b, 64-s chunk). Phases:
//  P0: summ fp32 -> bf16 LDS (A operand, reused by all 4 waves)
//  P1: per wave, 16(l) x 16(s) score tile via mfma_f32_16x16x32_bf16,
//      exp -> e_lds[s][l]; per-wave Z partial via shuffle -> zp
//  P2: per thread, unnormalized ctx[l][d-quad] += e[l][s]*mem[s][d] (fl4 FMA),
//      mem re-read served by L3; write part[blk][l][d], Zpart[blk][l]
__global__ __launch_bounds__(256) void k_fused(const float* __restrict__ mem,
                                               const float* __restrict__ summ,
                                               float* __restrict__ part,
                                               float* __restrict__ Zpart) {
    __shared__ short summ_l[LL * SPAD];   // 33 KB
    __shared__ float e_lds[64 * LL];      // 4 KB
    __shared__ float zp[4][LL];

    int blk = blockIdx.x;                 // 512 = 8 b x 64 chunks
    int b   = blk >> 6;
    int s0  = (blk & 63) << 6;
    int t    = threadIdx.x;
    int w    = t >> 6;
    int lane = t & 63;
    int o  = lane & 15;
    int qd = lane >> 4;

    // P0: stage summ as bf16 into LDS (coalesced fl4 reads, b64 LDS writes)
    for (int i = t; i < LL * DD / 4; i += 256) {
        int l = i >> 8, d = (i & 255) * 4;
        fl4 v = *(const fl4*)(summ + l * DD + d);
        short tmp[4];
        tmp[0] = f2bf(v[0]); tmp[1] = f2bf(v[1]);
        tmp[2] = f2bf(v[2]); tmp[3] = f2bf(v[3]);
        *(unsigned long long*)&summ_l[l * SPAD + d] = *(unsigned long long*)tmp;
    }
    __syncthreads();

    // P1: scores for rows s0 + w*16 .. +15
    const short* arow = summ_l + o * SPAD + qd * 8;                       // A: m=lane&15 -> l
    const float* mrow = mem + ((size_t)b * SS + s0 + w * 16 + o) * DD + qd * 8;  // B: n=lane&15 -> s

    fl4 acc = {0.f, 0.f, 0.f, 0.f};
    #pragma unroll 8
    for (int k = 0; k < DD; k += 32) {
        short8 a = *(const short8*)(arow + k);
        fl4 f0 = *(const fl4*)(mrow + k);
        fl4 f1 = *(const fl4*)(mrow + k + 4);
        short8 bb;
        bb[0] = f2bf(f0[0]); bb[1] = f2bf(f0[1]);
        bb[2] = f2bf(f0[2]); bb[3] = f2bf(f0[3]);
        bb[4] = f2bf(f1[0]); bb[5] = f2bf(f1[1]);
        bb[6] = f2bf(f1[2]); bb[7] = f2bf(f1[3]);
        acc = __builtin_amdgcn_mfma_f32_16x16x32_bf16(a, bb, acc, 0, 0, 0);
    }

    const float scale = 0.03125f;  // 1/sqrt(1024)
    fl4 ev;
    #pragma unroll
    for (int r = 0; r < 4; ++r) ev[r] = __expf(acc[r] * scale);
    // e_lds[s_local][l]: s_local = w*16+o, l = qd*4+r (r consecutive -> fl4 store)
    *(fl4*)&e_lds[(w * 16 + o) * LL + qd * 4] = ev;

    // Z partial: sum over the 16 s (o) within each qd group (xor 1,2,4,8 stay in-group)
    fl4 zs = ev;
    #pragma unroll
    for (int r = 0; r < 4; ++r) {
        float v = zs[r];
        v += __shfl_xor(v, 1, 64);
        v += __shfl_xor(v, 2, 64);
        v += __shfl_xor(v, 4, 64);
        v += __shfl_xor(v, 8, 64);
        zs[r] = v;
    }
    if (o == 0) *(fl4*)&zp[w][qd * 4] = zs;
    __syncthreads();

    // P2: ctx[l][d-quad] over the chunk's 64 s (mem re-read -> L3 hit)
    fl4 ctx[LL];
    #pragma unroll
    for (int l = 0; l < LL; ++l) ctx[l] = (fl4){0.f, 0.f, 0.f, 0.f};
    const float* mb = mem + ((size_t)b * SS + s0) * DD + t * 4;
    #pragma unroll 4
    for (int s = 0; s < 64; ++s) {
        fl4 m4 = *(const fl4*)(mb + (size_t)s * DD);
        const fl4* ee = (const fl4*)&e_lds[s * LL];   // same addr all lanes -> broadcast
        #pragma unroll
        for (int g = 0; g < 4; ++g) {
            fl4 e4 = ee[g];
            ctx[g * 4 + 0] += e4[0] * m4;
            ctx[g * 4 + 1] += e4[1] * m4;
            ctx[g * 4 + 2] += e4[2] * m4;
            ctx[g * 4 + 3] += e4[3] * m4;
        }
    }
    float* pp = part + (size_t)blk * LL * DD + t * 4;
    #pragma unroll
    for (int l = 0; l < LL; ++l) *(fl4*)(pp + l * DD) = ctx[l];
    if (t < LL) Zpart[blk * LL + t] = zp[0][t] + zp[1][t] + zp[2][t] + zp[3][t];
}

// out[b][d] = sum_l (w[l]/Z[b][l]) * sum_ch part[b*64+ch][l][d]
__global__ __launch_bounds__(256) void k_out(const float* __restrict__ part,
                                             const float* __restrict__ Zpart,
                                             const float* __restrict__ w,
                                             float* __restrict__ out) {
    int blkid = blockIdx.x;          // 128 = 8 b x 16 d-groups of 64
    int b  = blkid >> 4;
    int d0 = (blkid & 15) << 6;
    int t = threadIdx.x;
    __shared__ float zz[16][LL];
    __shared__ float coef[LL];
    __shared__ float red[4][64];

    int l = t & 15, cq = t >> 4;     // 16 ch-groups of 4
    float zsum = 0.f;
    #pragma unroll
    for (int j = 0; j < 4; ++j) zsum += Zpart[(b * 64 + cq * 4 + j) * LL + l];
    zz[cq][l] = zsum;
    __syncthreads();
    if (t < LL) {
        float Z = 0.f;
        #pragma unroll
        for (int g = 0; g < 16; ++g) Z += zz[g][t];
        coef[t] = w[t] / Z;
    }
    __syncthreads();

    float c[LL];
    #pragma unroll
    for (int i = 0; i < LL; ++i) c[i] = coef[i];
    int doff = t & 63, cg = t >> 6;  // 4 ch-groups of 16
    float accv = 0.f;
    for (int ch = cg * 16; ch < cg * 16 + 16; ++ch) {
        const float* pb = part + (size_t)(b * 64 + ch) * LL * DD + d0 + doff;
        #pragma unroll
        for (int l2 = 0; l2 < LL; ++l2) accv += c[l2] * pb[(size_t)l2 * DD];
    }
    red[cg][doff] = accv;
    __syncthreads();
    if (t < 64) out[b * DD + d0 + t] = red[0][t] + red[1][t] + red[2][t] + red[3][t];
}

extern "C" void kernel_launch(void* const* d_in, const int* in_sizes, int n_in,
                              void* d_out, int out_size, void* d_ws, size_t ws_size,
                              hipStream_t stream) {
    const float* mem  = (const float*)d_in[0];  // [8,4096,1024] fp32
    const float* summ = (const float*)d_in[1];  // [16,1024] fp32
    const float* w    = (const float*)d_in[2];  // [1,16] fp32
    float* out = (float*)d_out;                 // [8,1024] fp32

    char* ws = (char*)d_ws;
    float* Zpart = (float*)ws;                  // 32 KB (padded to 64 KB)
    float* part  = (float*)(ws + 64 * 1024);    // 32 MB

    k_fused<<<BB * 64, 256, 0, stream>>>(mem, summ, part, Zpart);
    k_out<<<BB * 16, 256, 0, stream>>>(part, Zpart, w, out);
}